// Round 12
// baseline (2250.937 us; speedup 1.0000x reference)
//
#include <hip/hip_runtime.h>
#include <stdint.h>

#define NN 8192
#define DD 64

// Static scratch for M1 = tanh(3(emb1@W1^T+b1)), M2 likewise. 4 MB total.
// (x = arange(N) is an identity gather -> d_in[0] never read.)
__device__ float g_M1[NN * DD];
__device__ float g_M2[NN * DD];

__device__ __forceinline__ uint32_t rotl32(uint32_t v, uint32_t s) {
  return (v << s) | (v >> (32u - s));
}

// PARTITIONABLE threefry noise — confirmed by r10 probe, validated r11 pass:
// counter (0,i), key (0,1), output fold x0^x1. Core KAT-verified (r5).
__device__ __forceinline__ uint32_t tf_bits_part(uint32_t i) {
  const uint32_t ks1 = 1u, ks2 = 0x1BD11BDBu;
  uint32_t x0 = 0u;
  uint32_t x1 = i + ks1;
#define TFR4(a,b,c,d) \
  x0 += x1; x1 = rotl32(x1,a); x1 ^= x0; \
  x0 += x1; x1 = rotl32(x1,b); x1 ^= x0; \
  x0 += x1; x1 = rotl32(x1,c); x1 ^= x0; \
  x0 += x1; x1 = rotl32(x1,d); x1 ^= x0;
  TFR4(13u,15u,26u,6u)   x0 += ks1; x1 += ks2 + 1u;
  TFR4(17u,29u,16u,24u)  x0 += ks2; x1 += 2u;
  TFR4(13u,15u,26u,6u)              x1 += ks1 + 3u;
  TFR4(17u,29u,16u,24u)  x0 += ks1; x1 += ks2 + 4u;
  TFR4(13u,15u,26u,6u)   x0 += ks2; x1 += 5u;
#undef TFR4
  return x0 ^ x1;
}

__device__ __forceinline__ float noise_at(uint32_t n) {
  uint32_t bits = tf_bits_part(n);
  float u = __fadd_rn(__uint_as_float((bits >> 9) | 0x3F800000u), -1.0f);
  return __fmul_rn(u, 0.01f);
}

// Confirmed family (r11 pass): XLA EmitFastTanh(with_fma=true), clamp
// +/-7.99881172180175781f, |x|<0.0004 passthrough. Bitwise ODD (used by the
// antisymmetry trick: tanh_fam(-t) == -tanh_fam(t) exactly).
__device__ __forceinline__ float tanh_fam(float x) {
  const float kClamp = 7.99881172180175781f;
  float ax = fabsf(x);
  float xc = fminf(fmaxf(x, -kClamp), kClamp);
  float s = __fmul_rn(xc, xc);
  float p = -2.76076847742355e-16f;
  p = fmaf(s, p, 2.00018790482477e-13f);
  p = fmaf(s, p, -8.60467152213735e-11f);
  p = fmaf(s, p, 5.12229709037114e-08f);
  p = fmaf(s, p, 1.48572235717979e-05f);
  p = fmaf(s, p, 6.37261928875436e-04f);
  p = fmaf(s, p, 4.89352455891786e-03f);
  p = __fmul_rn(xc, p);
  float q = 1.19825839466702e-06f;
  q = fmaf(s, q, 1.18534705686654e-04f);
  q = fmaf(s, q, 2.26843463243900e-03f);
  q = fmaf(s, q, 4.89352518554385e-03f);
  float r = p / q;
  return (ax < 0.0004f) ? x : r;
}

// ---------------- K1: M1/M2 ----------------
__global__ __launch_bounds__(256) void k1_M(
    const float* __restrict__ emb1, const float* __restrict__ emb2,
    const float* __restrict__ W1, const float* __restrict__ b1,
    const float* __restrict__ W2, const float* __restrict__ b2) {
  int g = blockIdx.x * 256 + threadIdx.x;
  int d = g & 63;
  int row = (g >> 6) & (NN - 1);
  int mat = g >> 19;
  const float* emb = mat ? emb2 : emb1;
  const float* W   = mat ? W2 : W1;
  const float* bv  = mat ? b2 : b1;
  float* outm      = mat ? g_M2 : g_M1;
  const float* mrow = emb + (size_t)row * DD;
  const float* wrow = W + d * DD;
  float p = 0.0f;
  #pragma unroll
  for (int k = 0; k < DD; ++k) p = fmaf(mrow[k], wrow[k], p);
  float t = __fmul_rn(3.0f, __fadd_rn(p, bv[d]));
  outm[row * DD + d] = tanh_fam(t);
}

// ---------------- K2: upper-triangular tiles only (antisymmetry) -----------
// A[i][j] = relu(tanh(3(d))) with d = M1_i.M2_j - M2_i.M1_j.
// d_ji == -d_ij bit-exactly (same products, same order, IEEE sub/odd-tanh),
// so tile (I,J), I<=J, also emits A[j][i] = relu(-u).
__global__ __launch_bounds__(256) void k2_A(float* __restrict__ out) {
  __shared__ __align__(16) float sm[4][32][68];
  const int tid = threadIdx.x;
  // decode blockIdx -> (by, bx), by <= bx, from triangular index
  int rev = 8255 - (int)blockIdx.x;
  int t = (int)((sqrtf(8.0f * (float)rev + 1.0f) - 1.0f) * 0.5f);
  while ((t + 1) * (t + 2) / 2 <= rev) ++t;
  while (t * (t + 1) / 2 > rev) --t;
  const int by = 127 - t;
  const int bx = 127 - (rev - t * (t + 1) / 2);
  const int i0 = by * 64, j0 = bx * 64;
  const int tn = tid & 15, tm = tid >> 4;
  float acc1[4][4], acc2[4][4];
  #pragma unroll
  for (int m = 0; m < 4; ++m)
    #pragma unroll
    for (int n = 0; n < 4; ++n) { acc1[m][n] = 0.0f; acc2[m][n] = 0.0f; }

  for (int ph = 0; ph < 2; ++ph) {
    const int kb = ph * 32;
    __syncthreads();
    {
      const int k = tid & 31;
      const int r0 = tid >> 5;
      #pragma unroll
      for (int it = 0; it < 8; ++it) {
        const int r = r0 * 8 + it;
        sm[0][k][r] = g_M1[(i0 + r) * DD + kb + k];
        sm[1][k][r] = g_M2[(i0 + r) * DD + kb + k];
        sm[2][k][r] = g_M1[(j0 + r) * DD + kb + k];
        sm[3][k][r] = g_M2[(j0 + r) * DD + kb + k];
      }
    }
    __syncthreads();
    #pragma unroll 8
    for (int k = 0; k < 32; ++k) {
      float a1[4], a2[4], b1v[4], b2v[4];
      *(float4*)a1  = *(const float4*)&sm[0][k][tm * 4];
      *(float4*)a2  = *(const float4*)&sm[1][k][tm * 4];
      *(float4*)b1v = *(const float4*)&sm[2][k][tn * 4];
      *(float4*)b2v = *(const float4*)&sm[3][k][tn * 4];
      #pragma unroll
      for (int m = 0; m < 4; ++m)
        #pragma unroll
        for (int n = 0; n < 4; ++n) {
          acc1[m][n] = fmaf(a1[m], b2v[n], acc1[m][n]);
          acc2[m][n] = fmaf(a2[m], b1v[n], acc2[m][n]);
        }
    }
  }
  float u[4][4];
  #pragma unroll
  for (int m = 0; m < 4; ++m) {
    float o[4];
    #pragma unroll
    for (int n = 0; n < 4; ++n) {
      float tt = __fmul_rn(3.0f, __fsub_rn(acc1[m][n], acc2[m][n]));
      u[m][n] = tanh_fam(tt);
      o[n] = fmaxf(u[m][n], 0.0f);
    }
    *(float4*)&out[(size_t)(i0 + tm * 4 + m) * NN + j0 + tn * 4] = *(float4*)o;
  }
  if (by != bx) { // mirror tile: A[j][i] = relu(-u)
    #pragma unroll
    for (int n = 0; n < 4; ++n) {
      float o[4];
      #pragma unroll
      for (int m = 0; m < 4; ++m) o[m] = fmaxf(-u[m][n], 0.0f);
      *(float4*)&out[(size_t)(j0 + tn * 4 + n) * NN + i0 + tm * 4] = *(float4*)o;
    }
  }
}

// ---------------- K3: per-row exact top-32 of (A+noise), single key pass ---
__global__ __launch_bounds__(256) void k3_topk(float* __restrict__ out) {
  __shared__ __align__(16) float arow[NN];     // 32 KB
  __shared__ uint32_t hist[256];               // 1 KB
  __shared__ uint32_t flags[256];              // 1 KB
  __shared__ uint32_t cand[3584];              // 14 KB: (kbOff<<13)|(8191-j)
  __shared__ uint32_t bc[512];                 // 2 KB boundary candidates
  __shared__ uint32_t smisc[8];                // 0:candcnt 1:bccnt 2:D 3:above 4:ok
  const int tid = threadIdx.x;
  const int row = blockIdx.x;
  const float* src = out + (size_t)row * NN;
  #pragma unroll
  for (int s = 0; s < 8; ++s) {
    int q = tid + 256 * s;
    *(float4*)&arow[q * 4] = *(const float4*)&src[q * 4];
  }
  hist[tid] = 0u; flags[tid] = 0u;
  if (tid < 8) smisc[tid] = 0u;
  __syncthreads();

  // Single pass: compute keys >= 1.0f once, histogram + store packed.
  // key < 1.01 -> kbOff = kb - 0x3F800000 < 2^17; pack with (8191-j) so that
  // descending order == (key desc, index asc) == stable top_k tie-break.
  #pragma unroll
  for (int s = 0; s < 32; ++s) {
    int j = tid + 256 * s;
    float a = arow[j];
    if (a >= 0.98f) {
      float key = __fadd_rn(a, noise_at((uint32_t)(row * NN + j)));
      uint32_t kb = __float_as_uint(key);
      if (kb >= 0x3F800000u) {
        uint32_t off = kb - 0x3F800000u;
        atomicAdd(&hist[off >> 9], 1u);
        uint32_t pos = atomicAdd(&smisc[0], 1u);
        if (pos < 3584u) cand[pos] = (off << 13) | (8191u - (uint32_t)j);
      }
    }
  }
  __syncthreads();

  if (tid < 64) { // descending suffix scan to find threshold bucket
    int bhi = 255 - 4 * tid;
    uint32_t s0 = hist[bhi] + hist[bhi - 1] + hist[bhi - 2] + hist[bhi - 3];
    uint32_t c = s0;
    #pragma unroll
    for (int dl = 1; dl < 64; dl <<= 1) {
      uint32_t t = __shfl_up(c, dl, 64);
      if (tid >= dl) c += t;
    }
    uint32_t total = __shfl(c, 63, 64);
    unsigned long long vote = __ballot(c >= 32u);
    if (total >= 32u && vote != 0ull) {
      int L = __builtin_ctzll(vote);
      if (tid == L) {
        uint32_t above = c - s0;
        int Dd = bhi - 3;
        #pragma unroll
        for (int qq = 0; qq < 4; ++qq) {
          int b = bhi - qq;
          uint32_t h = hist[b];
          if (above + h >= 32u) { Dd = b; break; }
          above += h;
        }
        smisc[2] = (uint32_t)Dd; smisc[3] = above; smisc[4] = 1u;
      }
    }
  }
  __syncthreads();

  bool ok = (smisc[4] != 0u) && (smisc[0] <= 3584u);
  const uint32_t Dd = smisc[2];
  const uint32_t above = smisc[3];
  if (ok) {
    const uint32_t cnt = smisc[0];
    for (uint32_t ci = tid; ci < cnt; ci += 256u) {
      uint32_t p = cand[ci];
      uint32_t bkt = p >> 22; // off>>9
      if (bkt > Dd) {
        uint32_t j = 8191u - (p & 8191u);
        atomicOr(&flags[j >> 5], 1u << (j & 31));
      } else if (bkt == Dd) {
        uint32_t pos = atomicAdd(&smisc[1], 1u);
        if (pos < 512u) bc[pos] = p;
      }
    }
    __syncthreads();
    if (tid == 0 && smisc[1] > 512u) smisc[4] = 0u;
    __syncthreads();
    ok = (smisc[4] != 0u);
    if (ok) {
      const uint32_t bcnt = smisc[1];
      const uint32_t need = 32u - above;
      for (uint32_t ci = tid; ci < bcnt; ci += 256u) {
        uint32_t me = bc[ci];
        uint32_t rank = 0;
        for (uint32_t o = 0; o < bcnt; ++o) rank += (bc[o] > me) ? 1u : 0u;
        if (rank < need) {
          uint32_t j = 8191u - (me & 8191u);
          atomicOr(&flags[j >> 5], 1u << (j & 31));
        }
      }
    }
    __syncthreads();
    ok = (smisc[4] != 0u);
  }

  if (!ok) { // exact slow fallback (pathological rows only)
    unsigned long long mykb[32];
    #pragma unroll
    for (int s = 0; s < 32; ++s) {
      int j = tid + 256 * s;
      uint32_t kb = __float_as_uint(
          __fadd_rn(arow[j], noise_at((uint32_t)(row * NN + j))));
      mykb[s] = ((unsigned long long)kb << 32) | (uint32_t)(~(uint32_t)j);
    }
    flags[tid] = 0u;
    __syncthreads();
    for (int it = 0; it < 32; ++it) {
      unsigned long long best = 0ull;
      #pragma unroll
      for (int s = 0; s < 32; ++s) {
        int j = tid + 256 * s;
        if (((flags[j >> 5] >> (j & 31)) & 1u) == 0u)
          if (mykb[s] > best) best = mykb[s];
      }
      // reuse cand[] as a 64-bit reduction scratch (256 * 8B = 2KB region)
      ((unsigned long long*)cand)[tid] = best;
      __syncthreads();
      if (tid == 0) {
        unsigned long long w = 0ull;
        for (int t2 = 0; t2 < 256; ++t2)
          if (((unsigned long long*)cand)[t2] > w) w = ((unsigned long long*)cand)[t2];
        uint32_t j = ~(uint32_t)w;
        flags[j >> 5] |= (1u << (j & 31));
      }
      __syncthreads();
    }
  }
  __syncthreads();

  float* dst = out + (size_t)row * NN;
  #pragma unroll
  for (int s = 0; s < 8; ++s) {
    int q = tid + 256 * s;
    int j = q * 4;
    float4 v = *(const float4*)&arow[j];
    uint32_t fw = flags[j >> 5] >> (j & 31);
    v.x = (fw & 1u) ? v.x : 0.0f;
    v.y = (fw & 2u) ? v.y : 0.0f;
    v.z = (fw & 4u) ? v.z : 0.0f;
    v.w = (fw & 8u) ? v.w : 0.0f;
    *(float4*)&dst[j] = v;
  }
}

extern "C" void kernel_launch(void* const* d_in, const int* in_sizes, int n_in,
                              void* d_out, int out_size, void* d_ws, size_t ws_size,
                              hipStream_t stream) {
  (void)in_sizes; (void)n_in; (void)d_ws; (void)ws_size; (void)out_size;
  const float* emb1 = (const float*)d_in[1];
  const float* emb2 = (const float*)d_in[2];
  const float* W1   = (const float*)d_in[3];
  const float* b1   = (const float*)d_in[4];
  const float* W2   = (const float*)d_in[5];
  const float* b2   = (const float*)d_in[6];
  float* out = (float*)d_out;

  hipLaunchKernelGGL(k1_M, dim3((2 * NN * DD) / 256), dim3(256), 0, stream,
                     emb1, emb2, W1, b1, W2, b2);
  hipLaunchKernelGGL(k2_A, dim3(8256), dim3(256), 0, stream, out);
  hipLaunchKernelGGL(k3_topk, dim3(NN), dim3(256), 0, stream, out);
}

// Round 13
// 414.912 us; speedup vs baseline: 5.4251x; 5.4251x over previous
//
#include <hip/hip_runtime.h>
#include <stdint.h>

#define NN 8192
#define DD 64

// Static scratch for M1 = tanh(3(emb1@W1^T+b1)), M2 likewise. 4 MB total.
// (x = arange(N) is an identity gather -> d_in[0] never read.)
__device__ float g_M1[NN * DD];
__device__ float g_M2[NN * DD];

__device__ __forceinline__ uint32_t rotl32(uint32_t v, uint32_t s) {
  return (v << s) | (v >> (32u - s));
}

// PARTITIONABLE threefry noise — confirmed r10 probe, validated r11/r12 pass:
// counter (0,i), key (0,1), output fold x0^x1. Core KAT-verified (r5).
__device__ __forceinline__ uint32_t tf_bits_part(uint32_t i) {
  const uint32_t ks1 = 1u, ks2 = 0x1BD11BDBu;
  uint32_t x0 = 0u;
  uint32_t x1 = i + ks1;
#define TFR4(a,b,c,d) \
  x0 += x1; x1 = rotl32(x1,a); x1 ^= x0; \
  x0 += x1; x1 = rotl32(x1,b); x1 ^= x0; \
  x0 += x1; x1 = rotl32(x1,c); x1 ^= x0; \
  x0 += x1; x1 = rotl32(x1,d); x1 ^= x0;
  TFR4(13u,15u,26u,6u)   x0 += ks1; x1 += ks2 + 1u;
  TFR4(17u,29u,16u,24u)  x0 += ks2; x1 += 2u;
  TFR4(13u,15u,26u,6u)              x1 += ks1 + 3u;
  TFR4(17u,29u,16u,24u)  x0 += ks1; x1 += ks2 + 4u;
  TFR4(13u,15u,26u,6u)   x0 += ks2; x1 += 5u;
#undef TFR4
  return x0 ^ x1;
}

__device__ __forceinline__ float noise_at(uint32_t n) {
  uint32_t bits = tf_bits_part(n);
  float u = __fadd_rn(__uint_as_float((bits >> 9) | 0x3F800000u), -1.0f);
  return __fmul_rn(u, 0.01f);
}

// Confirmed family (r11/r12 pass): XLA EmitFastTanh(with_fma=true), clamp
// +/-7.99881172180175781f, |x|<0.0004 passthrough. Bitwise ODD.
__device__ __forceinline__ float tanh_fam(float x) {
  const float kClamp = 7.99881172180175781f;
  float ax = fabsf(x);
  float xc = fminf(fmaxf(x, -kClamp), kClamp);
  float s = __fmul_rn(xc, xc);
  float p = -2.76076847742355e-16f;
  p = fmaf(s, p, 2.00018790482477e-13f);
  p = fmaf(s, p, -8.60467152213735e-11f);
  p = fmaf(s, p, 5.12229709037114e-08f);
  p = fmaf(s, p, 1.48572235717979e-05f);
  p = fmaf(s, p, 6.37261928875436e-04f);
  p = fmaf(s, p, 4.89352455891786e-03f);
  p = __fmul_rn(xc, p);
  float q = 1.19825839466702e-06f;
  q = fmaf(s, q, 1.18534705686654e-04f);
  q = fmaf(s, q, 2.26843463243900e-03f);
  q = fmaf(s, q, 4.89352518554385e-03f);
  float r = p / q;
  return (ax < 0.0004f) ? x : r;
}

// ---------------- K1: M1/M2 ----------------
__global__ __launch_bounds__(256) void k1_M(
    const float* __restrict__ emb1, const float* __restrict__ emb2,
    const float* __restrict__ W1, const float* __restrict__ b1,
    const float* __restrict__ W2, const float* __restrict__ b2) {
  int g = blockIdx.x * 256 + threadIdx.x;
  int d = g & 63;
  int row = (g >> 6) & (NN - 1);
  int mat = g >> 19;
  const float* emb = mat ? emb2 : emb1;
  const float* W   = mat ? W2 : W1;
  const float* bv  = mat ? b2 : b1;
  float* outm      = mat ? g_M2 : g_M1;
  const float* mrow = emb + (size_t)row * DD;
  const float* wrow = W + d * DD;
  float p = 0.0f;
  #pragma unroll
  for (int k = 0; k < DD; ++k) p = fmaf(mrow[k], wrow[k], p);
  float t = __fmul_rn(3.0f, __fadd_rn(p, bv[d]));
  outm[row * DD + d] = tanh_fam(t);
}

// ---------------- K2: upper-triangular tiles only (antisymmetry) -----------
// Measured-good in r12 (bit-exact pass). d_ji == -d_ij bit-exactly.
__global__ __launch_bounds__(256) void k2_A(float* __restrict__ out) {
  __shared__ __align__(16) float sm[4][32][68];
  const int tid = threadIdx.x;
  int rev = 8255 - (int)blockIdx.x;
  int t = (int)((sqrtf(8.0f * (float)rev + 1.0f) - 1.0f) * 0.5f);
  while ((t + 1) * (t + 2) / 2 <= rev) ++t;
  while (t * (t + 1) / 2 > rev) --t;
  const int by = 127 - t;
  const int bx = 127 - (rev - t * (t + 1) / 2);
  const int i0 = by * 64, j0 = bx * 64;
  const int tn = tid & 15, tm = tid >> 4;
  float acc1[4][4], acc2[4][4];
  #pragma unroll
  for (int m = 0; m < 4; ++m)
    #pragma unroll
    for (int n = 0; n < 4; ++n) { acc1[m][n] = 0.0f; acc2[m][n] = 0.0f; }

  for (int ph = 0; ph < 2; ++ph) {
    const int kb = ph * 32;
    __syncthreads();
    {
      const int k = tid & 31;
      const int r0 = tid >> 5;
      #pragma unroll
      for (int it = 0; it < 8; ++it) {
        const int r = r0 * 8 + it;
        sm[0][k][r] = g_M1[(i0 + r) * DD + kb + k];
        sm[1][k][r] = g_M2[(i0 + r) * DD + kb + k];
        sm[2][k][r] = g_M1[(j0 + r) * DD + kb + k];
        sm[3][k][r] = g_M2[(j0 + r) * DD + kb + k];
      }
    }
    __syncthreads();
    #pragma unroll 8
    for (int k = 0; k < 32; ++k) {
      float a1[4], a2[4], b1v[4], b2v[4];
      *(float4*)a1  = *(const float4*)&sm[0][k][tm * 4];
      *(float4*)a2  = *(const float4*)&sm[1][k][tm * 4];
      *(float4*)b1v = *(const float4*)&sm[2][k][tn * 4];
      *(float4*)b2v = *(const float4*)&sm[3][k][tn * 4];
      #pragma unroll
      for (int m = 0; m < 4; ++m)
        #pragma unroll
        for (int n = 0; n < 4; ++n) {
          acc1[m][n] = fmaf(a1[m], b2v[n], acc1[m][n]);
          acc2[m][n] = fmaf(a2[m], b1v[n], acc2[m][n]);
        }
    }
  }
  float u[4][4];
  #pragma unroll
  for (int m = 0; m < 4; ++m) {
    float o[4];
    #pragma unroll
    for (int n = 0; n < 4; ++n) {
      float tt = __fmul_rn(3.0f, __fsub_rn(acc1[m][n], acc2[m][n]));
      u[m][n] = tanh_fam(tt);
      o[n] = fmaxf(u[m][n], 0.0f);
    }
    *(float4*)&out[(size_t)(i0 + tm * 4 + m) * NN + j0 + tn * 4] = *(float4*)o;
  }
  if (by != bx) {
    #pragma unroll
    for (int n = 0; n < 4; ++n) {
      float o[4];
      #pragma unroll
      for (int m = 0; m < 4; ++m) o[m] = fmaxf(-u[m][n], 0.0f);
      *(float4*)&out[(size_t)(j0 + tn * 4 + n) * NN + i0 + tm * 4] = *(float4*)o;
    }
  }
}

// ---------------- K3: per-row exact top-32 (EXACT r11 version, measured) ----
__global__ __launch_bounds__(256) void k3_topk(float* __restrict__ out) {
  __shared__ __align__(16) float arow[NN];
  __shared__ uint32_t hist[256];
  __shared__ uint32_t flags[256];
  __shared__ __align__(16) unsigned long long cand[512];
  __shared__ uint32_t smisc[8];
  const int tid = threadIdx.x;
  const int row = blockIdx.x;
  const float* src = out + (size_t)row * NN;
  #pragma unroll
  for (int s = 0; s < 8; ++s) {
    int q = tid + 256 * s;
    *(float4*)&arow[q * 4] = *(const float4*)&src[q * 4];
  }
  hist[tid] = 0u; flags[tid] = 0u;
  if (tid < 8) smisc[tid] = 0u;
  __syncthreads();

  uint32_t qmask = 0u;
  #pragma unroll
  for (int s = 0; s < 32; ++s) {
    int j = tid + 256 * s;
    if (arow[j] >= 0.98f) qmask |= (1u << s);
  }
  {
    uint32_t qm = qmask;
    while (qm) {
      int s = __builtin_ctz(qm); qm &= qm - 1u;
      int j = tid + 256 * s;
      float key = __fadd_rn(arow[j], noise_at((uint32_t)(row * NN + j)));
      uint32_t kb = __float_as_uint(key);
      if (kb >= 0x3F800000u) {
        uint32_t bkt = (kb - 0x3F800000u) >> 9; if (bkt > 255u) bkt = 255u;
        atomicAdd(&hist[bkt], 1u);
      }
    }
  }
  __syncthreads();

  if (tid < 64) {
    int bhi = 255 - 4 * tid;
    uint32_t s0 = hist[bhi] + hist[bhi - 1] + hist[bhi - 2] + hist[bhi - 3];
    uint32_t c = s0;
    #pragma unroll
    for (int dl = 1; dl < 64; dl <<= 1) {
      uint32_t t = __shfl_up(c, dl, 64);
      if (tid >= dl) c += t;
    }
    uint32_t total = __shfl(c, 63, 64);
    unsigned long long vote = __ballot(c >= 32u);
    if (total >= 32u && vote != 0ull) {
      int L = __builtin_ctzll(vote);
      if (tid == L) {
        uint32_t above = c - s0;
        int Dd = bhi - 3;
        #pragma unroll
        for (int qq = 0; qq < 4; ++qq) {
          int b = bhi - qq;
          uint32_t h = hist[b];
          if (above + h >= 32u) { Dd = b; break; }
          above += h;
        }
        smisc[2] = (uint32_t)Dd; smisc[3] = above; smisc[4] = 1u;
      }
    }
  }
  __syncthreads();

  bool ok = (smisc[4] != 0u);
  const uint32_t Dd = smisc[2];
  const uint32_t above = smisc[3];
  if (ok) {
    uint32_t qm = qmask;
    while (qm) {
      int s = __builtin_ctz(qm); qm &= qm - 1u;
      int j = tid + 256 * s;
      float key = __fadd_rn(arow[j], noise_at((uint32_t)(row * NN + j)));
      uint32_t kb = __float_as_uint(key);
      if (kb >= 0x3F800000u) {
        uint32_t bkt = (kb - 0x3F800000u) >> 9; if (bkt > 255u) bkt = 255u;
        if (bkt > Dd) {
          atomicOr(&flags[j >> 5], 1u << (j & 31));
        } else if (bkt == Dd) {
          uint32_t pos = atomicAdd(&smisc[0], 1u);
          if (pos < 512u)
            cand[pos] = ((unsigned long long)kb << 32) | (uint32_t)(~(uint32_t)j);
        }
      }
    }
    __syncthreads();
    if (tid == 0 && smisc[0] > 512u) smisc[4] = 0u;
    __syncthreads();
    ok = (smisc[4] != 0u);
    if (ok) {
      const uint32_t cnt = smisc[0];
      const uint32_t need = 32u - above;
      for (uint32_t ci = tid; ci < cnt; ci += 256u) {
        unsigned long long me = cand[ci];
        uint32_t rank = 0;
        for (uint32_t o = 0; o < cnt; ++o) rank += (cand[o] > me) ? 1u : 0u;
        if (rank < need) {
          uint32_t j = ~(uint32_t)me;
          atomicOr(&flags[j >> 5], 1u << (j & 31));
        }
      }
    }
    __syncthreads();
    ok = (smisc[4] != 0u);
  }

  if (!ok) {
    uint32_t mykb[32];
    #pragma unroll
    for (int s = 0; s < 32; ++s) {
      int j = tid + 256 * s;
      mykb[s] = __float_as_uint(__fadd_rn(arow[j], noise_at((uint32_t)(row * NN + j))));
    }
    flags[tid] = 0u;
    __syncthreads();
    for (int it = 0; it < 32; ++it) {
      unsigned long long best = 0ull;
      #pragma unroll
      for (int s = 0; s < 32; ++s) {
        int j = tid + 256 * s;
        if (((flags[j >> 5] >> (j & 31)) & 1u) == 0u) {
          unsigned long long k64 =
              ((unsigned long long)mykb[s] << 32) | (uint32_t)(~(uint32_t)j);
          if (k64 > best) best = k64;
        }
      }
      cand[tid] = best;
      __syncthreads();
      if (tid == 0) {
        unsigned long long w = 0ull;
        for (int t2 = 0; t2 < 256; ++t2) if (cand[t2] > w) w = cand[t2];
        uint32_t j = ~(uint32_t)w;
        flags[j >> 5] |= (1u << (j & 31));
      }
      __syncthreads();
    }
  }
  __syncthreads();

  float* dst = out + (size_t)row * NN;
  #pragma unroll
  for (int s = 0; s < 8; ++s) {
    int q = tid + 256 * s;
    int j = q * 4;
    float4 v = *(const float4*)&arow[j];
    uint32_t fw = flags[j >> 5] >> (j & 31);
    v.x = (fw & 1u) ? v.x : 0.0f;
    v.y = (fw & 2u) ? v.y : 0.0f;
    v.z = (fw & 4u) ? v.z : 0.0f;
    v.w = (fw & 8u) ? v.w : 0.0f;
    *(float4*)&dst[j] = v;
  }
}

extern "C" void kernel_launch(void* const* d_in, const int* in_sizes, int n_in,
                              void* d_out, int out_size, void* d_ws, size_t ws_size,
                              hipStream_t stream) {
  (void)in_sizes; (void)n_in; (void)d_ws; (void)ws_size; (void)out_size;
  const float* emb1 = (const float*)d_in[1];
  const float* emb2 = (const float*)d_in[2];
  const float* W1   = (const float*)d_in[3];
  const float* b1   = (const float*)d_in[4];
  const float* W2   = (const float*)d_in[5];
  const float* b2   = (const float*)d_in[6];
  float* out = (float*)d_out;

  hipLaunchKernelGGL(k1_M, dim3((2 * NN * DD) / 256), dim3(256), 0, stream,
                     emb1, emb2, W1, b1, W2, b2);
  hipLaunchKernelGGL(k2_A, dim3(8256), dim3(256), 0, stream, out);
  hipLaunchKernelGGL(k3_topk, dim3(NN), dim3(256), 0, stream, out);
}

// Round 14
// 357.579 us; speedup vs baseline: 6.2949x; 1.1603x over previous
//
#include <hip/hip_runtime.h>
#include <stdint.h>

#define NN 8192
#define DD 64

// Static scratch for M1 = tanh(3(emb1@W1^T+b1)), M2 likewise. 4 MB total.
// (x = arange(N) is an identity gather -> d_in[0] never read.)
__device__ float g_M1[NN * DD];
__device__ float g_M2[NN * DD];

__device__ __forceinline__ uint32_t rotl32(uint32_t v, uint32_t s) {
  return (v << s) | (v >> (32u - s));
}

// PARTITIONABLE threefry noise — confirmed r10 probe, validated r11-r13 pass:
// counter (0,i), key (0,1), output fold x0^x1. Core KAT-verified (r5).
__device__ __forceinline__ uint32_t tf_bits_part(uint32_t i) {
  const uint32_t ks1 = 1u, ks2 = 0x1BD11BDBu;
  uint32_t x0 = 0u;
  uint32_t x1 = i + ks1;
#define TFR4(a,b,c,d) \
  x0 += x1; x1 = rotl32(x1,a); x1 ^= x0; \
  x0 += x1; x1 = rotl32(x1,b); x1 ^= x0; \
  x0 += x1; x1 = rotl32(x1,c); x1 ^= x0; \
  x0 += x1; x1 = rotl32(x1,d); x1 ^= x0;
  TFR4(13u,15u,26u,6u)   x0 += ks1; x1 += ks2 + 1u;
  TFR4(17u,29u,16u,24u)  x0 += ks2; x1 += 2u;
  TFR4(13u,15u,26u,6u)              x1 += ks1 + 3u;
  TFR4(17u,29u,16u,24u)  x0 += ks1; x1 += ks2 + 4u;
  TFR4(13u,15u,26u,6u)   x0 += ks2; x1 += 5u;
#undef TFR4
  return x0 ^ x1;
}

__device__ __forceinline__ float noise_at(uint32_t n) {
  uint32_t bits = tf_bits_part(n);
  float u = __fadd_rn(__uint_as_float((bits >> 9) | 0x3F800000u), -1.0f);
  return __fmul_rn(u, 0.01f);
}

// Confirmed family (r11-r13 pass): XLA EmitFastTanh(with_fma=true), clamp
// +/-7.99881172180175781f, |x|<0.0004 passthrough. Bitwise ODD.
__device__ __forceinline__ float tanh_fam(float x) {
  const float kClamp = 7.99881172180175781f;
  float ax = fabsf(x);
  float xc = fminf(fmaxf(x, -kClamp), kClamp);
  float s = __fmul_rn(xc, xc);
  float p = -2.76076847742355e-16f;
  p = fmaf(s, p, 2.00018790482477e-13f);
  p = fmaf(s, p, -8.60467152213735e-11f);
  p = fmaf(s, p, 5.12229709037114e-08f);
  p = fmaf(s, p, 1.48572235717979e-05f);
  p = fmaf(s, p, 6.37261928875436e-04f);
  p = fmaf(s, p, 4.89352455891786e-03f);
  p = __fmul_rn(xc, p);
  float q = 1.19825839466702e-06f;
  q = fmaf(s, q, 1.18534705686654e-04f);
  q = fmaf(s, q, 2.26843463243900e-03f);
  q = fmaf(s, q, 4.89352518554385e-03f);
  float r = p / q;
  return (ax < 0.0004f) ? x : r;
}

// ---------------- K1: M1/M2 ----------------
__global__ __launch_bounds__(256) void k1_M(
    const float* __restrict__ emb1, const float* __restrict__ emb2,
    const float* __restrict__ W1, const float* __restrict__ b1,
    const float* __restrict__ W2, const float* __restrict__ b2) {
  int g = blockIdx.x * 256 + threadIdx.x;
  int d = g & 63;
  int row = (g >> 6) & (NN - 1);
  int mat = g >> 19;
  const float* emb = mat ? emb2 : emb1;
  const float* W   = mat ? W2 : W1;
  const float* bv  = mat ? b2 : b1;
  float* outm      = mat ? g_M2 : g_M1;
  const float* mrow = emb + (size_t)row * DD;
  const float* wrow = W + d * DD;
  float p = 0.0f;
  #pragma unroll
  for (int k = 0; k < DD; ++k) p = fmaf(mrow[k], wrow[k], p);
  float t = __fmul_rn(3.0f, __fadd_rn(p, bv[d]));
  outm[row * DD + d] = tanh_fam(t);
}

// ---------------- K2: upper-triangular tiles only (antisymmetry) -----------
// Measured-good in r12/r13 (bit-exact pass). d_ji == -d_ij bit-exactly.
__global__ __launch_bounds__(256) void k2_A(float* __restrict__ out) {
  __shared__ __align__(16) float sm[4][32][68];
  const int tid = threadIdx.x;
  int rev = 8255 - (int)blockIdx.x;
  int t = (int)((sqrtf(8.0f * (float)rev + 1.0f) - 1.0f) * 0.5f);
  while ((t + 1) * (t + 2) / 2 <= rev) ++t;
  while (t * (t + 1) / 2 > rev) --t;
  const int by = 127 - t;
  const int bx = 127 - (rev - t * (t + 1) / 2);
  const int i0 = by * 64, j0 = bx * 64;
  const int tn = tid & 15, tm = tid >> 4;
  float acc1[4][4], acc2[4][4];
  #pragma unroll
  for (int m = 0; m < 4; ++m)
    #pragma unroll
    for (int n = 0; n < 4; ++n) { acc1[m][n] = 0.0f; acc2[m][n] = 0.0f; }

  for (int ph = 0; ph < 2; ++ph) {
    const int kb = ph * 32;
    __syncthreads();
    {
      const int k = tid & 31;
      const int r0 = tid >> 5;
      #pragma unroll
      for (int it = 0; it < 8; ++it) {
        const int r = r0 * 8 + it;
        sm[0][k][r] = g_M1[(i0 + r) * DD + kb + k];
        sm[1][k][r] = g_M2[(i0 + r) * DD + kb + k];
        sm[2][k][r] = g_M1[(j0 + r) * DD + kb + k];
        sm[3][k][r] = g_M2[(j0 + r) * DD + kb + k];
      }
    }
    __syncthreads();
    #pragma unroll 8
    for (int k = 0; k < 32; ++k) {
      float a1[4], a2[4], b1v[4], b2v[4];
      *(float4*)a1  = *(const float4*)&sm[0][k][tm * 4];
      *(float4*)a2  = *(const float4*)&sm[1][k][tm * 4];
      *(float4*)b1v = *(const float4*)&sm[2][k][tn * 4];
      *(float4*)b2v = *(const float4*)&sm[3][k][tn * 4];
      #pragma unroll
      for (int m = 0; m < 4; ++m)
        #pragma unroll
        for (int n = 0; n < 4; ++n) {
          acc1[m][n] = fmaf(a1[m], b2v[n], acc1[m][n]);
          acc2[m][n] = fmaf(a2[m], b1v[n], acc2[m][n]);
        }
    }
  }
  float u[4][4];
  #pragma unroll
  for (int m = 0; m < 4; ++m) {
    float o[4];
    #pragma unroll
    for (int n = 0; n < 4; ++n) {
      float tt = __fmul_rn(3.0f, __fsub_rn(acc1[m][n], acc2[m][n]));
      u[m][n] = tanh_fam(tt);
      o[n] = fmaxf(u[m][n], 0.0f);
    }
    *(float4*)&out[(size_t)(i0 + tm * 4 + m) * NN + j0 + tn * 4] = *(float4*)o;
  }
  if (by != bx) {
    #pragma unroll
    for (int n = 0; n < 4; ++n) {
      float o[4];
      #pragma unroll
      for (int m = 0; m < 4; ++m) o[m] = fmaxf(-u[m][n], 0.0f);
      *(float4*)&out[(size_t)(j0 + tn * 4 + n) * NN + i0 + tm * 4] = *(float4*)o;
    }
  }
}

// ---------------- K3: top-32 with bucket-byte cache (1 threefry pass) ------
__global__ __launch_bounds__(256) void k3_topk(float* __restrict__ out) {
  __shared__ __align__(16) float arow[NN];              // 32 KB
  __shared__ uint32_t hist[256];                        // 1 KB
  __shared__ uint32_t flags[256];                       // 1 KB
  __shared__ __align__(16) unsigned long long cand[512];// 4 KB
  __shared__ uint32_t bkt8[NN / 4];                     // 8 KB bucket bytes
  __shared__ uint32_t smisc[8];
  const int tid = threadIdx.x;
  const int row = blockIdx.x;
  const float* src = out + (size_t)row * NN;
  #pragma unroll
  for (int s = 0; s < 8; ++s) {
    int q = tid + 256 * s;
    *(float4*)&arow[q * 4] = *(const float4*)&src[q * 4];
    bkt8[q] = 0xFFFFFFFFu; // sentinel: no key (legit buckets <= ~164 < 254)
  }
  hist[tid] = 0u; flags[tid] = 0u;
  if (tid < 8) smisc[tid] = 0u;
  __syncthreads();

  // Pass 1 (only threefry pass): sparse ctz loop over a>=0.98 entries;
  // histogram + cache the 8-bit bucket id per slot.
  uint32_t qmask = 0u;
  #pragma unroll
  for (int s = 0; s < 32; ++s) {
    int j = tid + 256 * s;
    if (arow[j] >= 0.98f) qmask |= (1u << s);
  }
  {
    uint32_t qm = qmask;
    while (qm) {
      int s = __builtin_ctz(qm); qm &= qm - 1u;
      int j = tid + 256 * s;
      float key = __fadd_rn(arow[j], noise_at((uint32_t)(row * NN + j)));
      uint32_t kb = __float_as_uint(key);
      if (kb >= 0x3F800000u) {
        uint32_t bkt = (kb - 0x3F800000u) >> 9; if (bkt > 254u) bkt = 254u;
        atomicAdd(&hist[bkt], 1u);
        ((uint8_t*)bkt8)[j] = (uint8_t)bkt;
      }
    }
  }
  __syncthreads();

  if (tid < 64) { // descending suffix scan to find threshold bucket
    int bhi = 255 - 4 * tid;
    uint32_t s0 = hist[bhi] + hist[bhi - 1] + hist[bhi - 2] + hist[bhi - 3];
    uint32_t c = s0;
    #pragma unroll
    for (int dl = 1; dl < 64; dl <<= 1) {
      uint32_t t = __shfl_up(c, dl, 64);
      if (tid >= dl) c += t;
    }
    uint32_t total = __shfl(c, 63, 64);
    unsigned long long vote = __ballot(c >= 32u);
    if (total >= 32u && vote != 0ull) {
      int L = __builtin_ctzll(vote);
      if (tid == L) {
        uint32_t above = c - s0;
        int Dd = bhi - 3;
        #pragma unroll
        for (int qq = 0; qq < 4; ++qq) {
          int b = bhi - qq;
          uint32_t h = hist[b];
          if (above + h >= 32u) { Dd = b; break; }
          above += h;
        }
        smisc[2] = (uint32_t)Dd; smisc[3] = above; smisc[4] = 1u;
      }
    }
  }
  __syncthreads();

  bool ok = (smisc[4] != 0u);
  const uint32_t Dd = smisc[2];
  const uint32_t above = smisc[3];
  if (ok) {
    // Pass 2: scan cached bucket bytes; threefry ONLY for boundary bucket.
    #pragma unroll
    for (int s = 0; s < 8; ++s) {
      int d = tid + 256 * s;
      uint32_t w = bkt8[d];
      if (w == 0xFFFFFFFFu) continue;
      #pragma unroll
      for (int b = 0; b < 4; ++b) {
        uint32_t bk = (w >> (8 * b)) & 255u;
        if (bk == 255u) continue;
        uint32_t j = (uint32_t)(d * 4 + b);
        if (bk > Dd) {
          atomicOr(&flags[j >> 5], 1u << (j & 31));
        } else if (bk == Dd) {
          uint32_t kb = __float_as_uint(
              __fadd_rn(arow[j], noise_at((uint32_t)(row * NN + j))));
          uint32_t pos = atomicAdd(&smisc[0], 1u);
          if (pos < 512u)
            cand[pos] = ((unsigned long long)kb << 32) | (uint32_t)(~j);
        }
      }
    }
    __syncthreads();
    if (tid == 0 && smisc[0] > 512u) smisc[4] = 0u;
    __syncthreads();
    ok = (smisc[4] != 0u);
    if (ok) {
      const uint32_t cnt = smisc[0];
      const uint32_t need = 32u - above;
      for (uint32_t ci = tid; ci < cnt; ci += 256u) {
        unsigned long long me = cand[ci];
        uint32_t rank = 0;
        for (uint32_t o = 0; o < cnt; ++o) rank += (cand[o] > me) ? 1u : 0u;
        if (rank < need) {
          uint32_t j = ~(uint32_t)me;
          atomicOr(&flags[j >> 5], 1u << (j & 31));
        }
      }
    }
    __syncthreads();
    ok = (smisc[4] != 0u);
  }

  if (!ok) { // exact slow fallback (pathological rows only)
    uint32_t mykb[32];
    #pragma unroll
    for (int s = 0; s < 32; ++s) {
      int j = tid + 256 * s;
      mykb[s] = __float_as_uint(__fadd_rn(arow[j], noise_at((uint32_t)(row * NN + j))));
    }
    flags[tid] = 0u;
    __syncthreads();
    for (int it = 0; it < 32; ++it) {
      unsigned long long best = 0ull;
      #pragma unroll
      for (int s = 0; s < 32; ++s) {
        int j = tid + 256 * s;
        if (((flags[j >> 5] >> (j & 31)) & 1u) == 0u) {
          unsigned long long k64 =
              ((unsigned long long)mykb[s] << 32) | (uint32_t)(~(uint32_t)j);
          if (k64 > best) best = k64;
        }
      }
      cand[tid] = best;
      __syncthreads();
      if (tid == 0) {
        unsigned long long w = 0ull;
        for (int t2 = 0; t2 < 256; ++t2) if (cand[t2] > w) w = cand[t2];
        uint32_t j = ~(uint32_t)w;
        flags[j >> 5] |= (1u << (j & 31));
      }
      __syncthreads();
    }
  }
  __syncthreads();

  float* dst = out + (size_t)row * NN;
  #pragma unroll
  for (int s = 0; s < 8; ++s) {
    int q = tid + 256 * s;
    int j = q * 4;
    float4 v = *(const float4*)&arow[j];
    uint32_t fw = flags[j >> 5] >> (j & 31);
    v.x = (fw & 1u) ? v.x : 0.0f;
    v.y = (fw & 2u) ? v.y : 0.0f;
    v.z = (fw & 4u) ? v.z : 0.0f;
    v.w = (fw & 8u) ? v.w : 0.0f;
    *(float4*)&dst[j] = v;
  }
}

extern "C" void kernel_launch(void* const* d_in, const int* in_sizes, int n_in,
                              void* d_out, int out_size, void* d_ws, size_t ws_size,
                              hipStream_t stream) {
  (void)in_sizes; (void)n_in; (void)d_ws; (void)ws_size; (void)out_size;
  const float* emb1 = (const float*)d_in[1];
  const float* emb2 = (const float*)d_in[2];
  const float* W1   = (const float*)d_in[3];
  const float* b1   = (const float*)d_in[4];
  const float* W2   = (const float*)d_in[5];
  const float* b2   = (const float*)d_in[6];
  float* out = (float*)d_out;

  hipLaunchKernelGGL(k1_M, dim3((2 * NN * DD) / 256), dim3(256), 0, stream,
                     emb1, emb2, W1, b1, W2, b2);
  hipLaunchKernelGGL(k2_A, dim3(8256), dim3(256), 0, stream, out);
  hipLaunchKernelGGL(k3_topk, dim3(NN), dim3(256), 0, stream, out);
}